// Round 3
// baseline (1029.011 us; speedup 1.0000x reference)
//
#include <hip/hip_runtime.h>
#include <math.h>

#define BB 2
#define NN 512
#define SDIM 384
#define ZDIM 128
#define HH 12
#define CDIM 16
#define PQ 4
#define PV 8
#define BN (BB*NN)        // 1024
#define CATD 2112

#define WL  0.57735026918962576f
#define LAM 0.06804138174397717f   // wL*wC/2, wC = sqrt(2/(9*PQ))

// ---- workspace layout (float offsets) ----
#define OFF_Q    0                         // [1024][192] rows
#define OFF_QP   196608                    // [1024][144] rows
#define OFF_QQ   344064                    // [1024][12]
#define OFF_KT4  356352                    // f4: [2][48][512]  (c4-group major, n minor)
#define OFF_KPT4 552960                    // f4: [2][36][512]
#define OFF_KKT  700416                    // [2][12][512]
#define OFF_V    712704                    // [1024][192] rows (f4 view [1024][48])
#define OFF_VP   909312                    // [1024][288] rows (f4 view [1024][72])
#define OFF_BIAS 1204224                   // [2][512 i][12 h][512 j]
#define OFF_CAT  7495680                   // [1024][2112]

__device__ __forceinline__ float dot4(float4 a, float4 b) {
    return a.x*b.x + a.y*b.y + a.z*b.z + a.w*b.w;
}
__device__ __forceinline__ void fma4(float4& a, float s, float4 b) {
    a.x += s*b.x; a.y += s*b.y; a.z += s*b.z; a.w += s*b.w;
}
__device__ __forceinline__ void add4(float4& a, float4 b) {
    a.x += b.x; a.y += b.y; a.z += b.z; a.w += b.w;
}

// ---------------- Kernel 1: projections + frame transform -------------------
// 2 rows per block, 512 blocks, 512 threads; tasks = 2 rows x 288 f4-cols.
__global__ __launch_bounds__(512) void k_proj(
    const float* __restrict__ s, const float* __restrict__ Rg, const float* __restrict__ tg,
    const float* __restrict__ Wq, const float* __restrict__ Wk, const float* __restrict__ Wv,
    const float* __restrict__ Wqp, const float* __restrict__ Wkp, const float* __restrict__ Wvp,
    float* __restrict__ ws)
{
    __shared__ float4 pL4[2][144];   // point projections (local frame)
    __shared__ float  sqL[2][96];    // |qp|^2 [0:48), |kp|^2 [48:96)
    __shared__ float  Rt[2][12];
    const int t = threadIdx.x;
    const int n0 = blockIdx.x * 2;
    const int b  = n0 >> 9;
    const int nloc = n0 & 511;

    if (t < 24) {
        int rr = t / 12, c = t % 12;
        Rt[rr][c] = (c < 9) ? Rg[(n0+rr)*9 + c] : tg[(n0+rr)*3 + (c-9)];
    }
    __syncthreads();

    float4* Q4g  = (float4*)(ws + OFF_Q);
    float4* V4g  = (float4*)(ws + OFF_V);
    float4* KT4g = (float4*)(ws + OFF_KT4);

    for (int task = t; task < 576; task += 512) {
        const int row = (task >= 288) ? 1 : 0;
        const int col = task - row*288;
        const float* srow = s + (size_t)(n0+row)*SDIM;
        const float4* W4; int wc4, ld4, dst;
        if (col < 48)       { W4 = (const float4*)Wq;  wc4 = col;     ld4 = 48; dst = 0; }
        else if (col < 96)  { W4 = (const float4*)Wk;  wc4 = col-48;  ld4 = 48; dst = 1; }
        else if (col < 144) { W4 = (const float4*)Wv;  wc4 = col-96;  ld4 = 48; dst = 2; }
        else if (col < 180) { W4 = (const float4*)Wqp; wc4 = col-144; ld4 = 36; dst = 3; }
        else if (col < 216) { W4 = (const float4*)Wkp; wc4 = col-180; ld4 = 36; dst = 4; }
        else                { W4 = (const float4*)Wvp; wc4 = col-216; ld4 = 72; dst = 5; }
        float4 acc = {0,0,0,0};
        #pragma unroll 16
        for (int r = 0; r < SDIM; ++r) {
            fma4(acc, srow[r], W4[r*ld4 + wc4]);
        }
        const int bn = n0 + row;
        if (dst == 0) {
            Q4g[(size_t)bn*48 + wc4] = acc;
        } else if (dst == 1) {
            KT4g[((size_t)(b*48 + wc4))*512 + nloc + row] = acc;
        } else if (dst == 2) {
            V4g[(size_t)bn*48 + wc4] = acc;
        } else if (dst == 3) {
            pL4[row][wc4] = acc;
        } else if (dst == 4) {
            pL4[row][36+wc4] = acc;
        } else {
            pL4[row][72+wc4] = acc;
        }
    }
    __syncthreads();

    // local -> global frame
    if (t < 384) {
        int rr = t / 192, pt = t % 192;
        const float* pl = (const float*)pL4[rr];
        int off = (pt < 48) ? pt*3 : (pt < 96 ? 144 + (pt-48)*3 : 288 + (pt-96)*3);
        float p0 = pl[off], p1 = pl[off+1], p2 = pl[off+2];
        const float* R = Rt[rr];
        float g0 = R[0]*p0 + R[1]*p1 + R[2]*p2 + R[9];
        float g1 = R[3]*p0 + R[4]*p1 + R[5]*p2 + R[10];
        float g2 = R[6]*p0 + R[7]*p1 + R[8]*p2 + R[11];
        int bn = n0 + rr, n = bn & 511;
        if (pt < 48) {
            int o = pt*3;
            float* d = ws + OFF_QP + (size_t)bn*144 + o;
            d[0] = g0; d[1] = g1; d[2] = g2;
            sqL[rr][pt] = g0*g0 + g1*g1 + g2*g2;
        } else if (pt < 96) {
            int pc = (pt-48)*3;
            float gg[3] = {g0,g1,g2};
            #pragma unroll
            for (int x = 0; x < 3; ++x) {
                int pcx = pc + x;
                ws[OFF_KPT4 + (((size_t)(b*36 + (pcx>>2)))*512 + n)*4 + (pcx&3)] = gg[x];
            }
            sqL[rr][pt] = g0*g0 + g1*g1 + g2*g2;
        } else {
            int o = (pt-96)*3;
            float* d = ws + OFF_VP + (size_t)bn*288 + o;
            d[0] = g0; d[1] = g1; d[2] = g2;
        }
    }
    __syncthreads();

    if (t < 48) {
        int rr = t / 24, u = t % 24;
        int bn = n0 + rr, n = bn & 511;
        if (u < 12) {
            float sm = sqL[rr][u*4] + sqL[rr][u*4+1] + sqL[rr][u*4+2] + sqL[rr][u*4+3];
            ws[OFF_QQ + (size_t)bn*12 + u] = sm;
        } else {
            int h = u - 12;
            float sm = sqL[rr][48+h*4] + sqL[rr][48+h*4+1] + sqL[rr][48+h*4+2] + sqL[rr][48+h*4+3];
            ws[OFF_KKT + ((size_t)(b*12 + h))*512 + n] = sm;
        }
    }
}

// ---------------- Kernel 2: pair bias, LDS-staged coalesced -----------------
// 64 pairs/block, 8192 blocks. z staged coalesced into XOR-swizzled LDS,
// per-thread (pair, k-quarter) partials, LDS reduce, coalesced writes.
__global__ __launch_bounds__(256) void k_bias(
    const float* __restrict__ z, const float* __restrict__ Wb, float* __restrict__ ws)
{
    __shared__ float4 zs[2048];          // 32 KB: [k4][pair ^ k4]
    __shared__ float  pmL[4*64*13];      // partials, pad 13 to break banks
    const int t = threadIdx.x;
    const size_t tile = (size_t)blockIdx.x * 64;
    const float4* z4 = (const float4*)z;

    #pragma unroll
    for (int r = 0; r < 8; ++r) {
        int g = t + 256*r;
        int pl = g >> 5, k4 = g & 31;
        zs[k4*64 + (pl ^ k4)] = z4[(tile + pl)*32 + k4];   // 1 KB/wave contiguous
    }
    __syncthreads();

    const int pl = t & 63, kq = t >> 6;
    float acc[HH];
    #pragma unroll
    for (int h = 0; h < HH; ++h) acc[h] = 0.f;
    #pragma unroll
    for (int m = 0; m < 8; ++m) {
        int k4 = kq*8 + m;
        float4 zv = zs[k4*64 + (pl ^ k4)];
        const float* wb = Wb + k4*48;      // uniform -> scalar loads
        #pragma unroll
        for (int h = 0; h < HH; ++h)
            acc[h] += zv.x*wb[h] + zv.y*wb[12+h] + zv.z*wb[24+h] + zv.w*wb[36+h];
    }
    #pragma unroll
    for (int h = 0; h < HH; ++h)
        pmL[(kq*64 + pl)*13 + h] = acc[h];
    __syncthreads();

    #pragma unroll
    for (int r = 0; r < 3; ++r) {
        int v = t + 256*r;                 // 0..767 = 12 h x 64 pairs
        int h = v >> 6, pl2 = v & 63;
        float sm = pmL[(0*64+pl2)*13 + h] + pmL[(1*64+pl2)*13 + h]
                 + pmL[(2*64+pl2)*13 + h] + pmL[(3*64+pl2)*13 + h];
        size_t pair = tile + pl2;
        int bi = (int)(pair >> 9), j = (int)(pair & 511);
        ws[OFF_BIAS + (size_t)bi*(HH*512) + h*512 + j] = sm;   // coalesced per h
    }
}

// ---------------- Kernel 3: fused attention per (b,i) -----------------------
__global__ __launch_bounds__(512, 4) void k_attn(
    const float* __restrict__ z, const float* __restrict__ Rg, const float* __restrict__ tg,
    const float* __restrict__ hw, float* __restrict__ ws)
{
    __shared__ __align__(16) float aL[HH*516];   // logits -> attention, stride 516
    __shared__ float4 optgS4[72];
    __shared__ float RiL[9], tiL[3];

    const int t = threadIdx.x;
    const int bi = blockIdx.x;
    const int b = bi >> 9;

    if (t < 9)             RiL[t]   = Rg[bi*9 + t];
    if (t >= 9 && t < 12)  tiL[t-9] = tg[bi*3 + (t-9)];

    // ---- phase A: logits, thread <-> j; bias/kk prefetched per 4-head group
    {
        const int j = t;
        const float4* Q4u  = (const float4*)(ws + OFF_Q  + (size_t)bi*192);
        const float4* QP4u = (const float4*)(ws + OFF_QP + (size_t)bi*144);
        const float*  QQu  = ws + OFF_QQ + (size_t)bi*12;
        const float4* KT4  = (const float4*)(ws + OFF_KT4)  + (size_t)b*48*512;
        const float4* KPT4 = (const float4*)(ws + OFF_KPT4) + (size_t)b*36*512;
        const float*  KKT  = ws + OFF_KKT  + (size_t)b*12*512;
        const float*  BI   = ws + OFF_BIAS + (size_t)bi*HH*512;
        for (int hg = 0; hg < 3; ++hg) {
            float bv[4], kv[4];
            #pragma unroll
            for (int u = 0; u < 4; ++u) {
                bv[u] = BI[(hg*4+u)*512 + j];
                kv[u] = KKT[(hg*4+u)*512 + j];
            }
            #pragma unroll
            for (int u = 0; u < 4; ++u) {
                const int h = hg*4 + u;
                float x = hw[h];
                float gam = (x > 20.f) ? x : log1pf(__expf(x));
                float scal = 0.f, qk = 0.f;
                #pragma unroll
                for (int cg = 0; cg < 4; ++cg)
                    scal += dot4(Q4u[h*4+cg], KT4[(h*4+cg)*512 + j]);
                #pragma unroll
                for (int pg = 0; pg < 3; ++pg)
                    qk += dot4(QP4u[h*3+pg], KPT4[(h*3+pg)*512 + j]);
                float dist2 = QQu[h] + kv[u] - 2.f*qk;
                aL[h*516 + j] = WL*(scal*0.25f + bv[u]) - LAM*gam*dist2;
            }
        }
    }
    __syncthreads();

    // ---- phase B: softmax per head ----
    {
        const int w = t >> 6, lane = t & 63;
        for (int h = w; h < HH; h += 8) {
            float* row = aL + h*516;
            float m = -1e30f;
            #pragma unroll
            for (int k = 0; k < 8; ++k) m = fmaxf(m, row[lane + 64*k]);
            #pragma unroll
            for (int off = 32; off > 0; off >>= 1) m = fmaxf(m, __shfl_xor(m, off));
            float ssum = 0.f;
            #pragma unroll
            for (int k = 0; k < 8; ++k) {
                float e = __expf(row[lane + 64*k] - m);
                row[lane + 64*k] = e;
                ssum += e;
            }
            #pragma unroll
            for (int off = 32; off > 0; off >>= 1) ssum += __shfl_xor(ssum, off);
            float inv = 1.f / ssum;
            #pragma unroll
            for (int k = 0; k < 8; ++k) row[lane + 64*k] *= inv;
        }
    }
    __syncthreads();

    // ---- phase C: accumulate opair/o/opt_g; 3 j-segments x 168 slot-threads
    // segments: [0,176) [176,352) [352,512)
    float4 acc0 = {0,0,0,0}, acc1 = {0,0,0,0}, acc2 = {0,0,0,0};
    int seg = 0, u = 0, typ = 3, hg = 0;
    if (t < 504) {
        seg = (t >= 336) ? 2 : (t >= 168) ? 1 : 0;
        u = t - seg*168;
        const int j0 = seg*176, j1 = (seg == 2) ? 512 : j0 + 176;
        if (u < 128) {
            typ = 0; hg = u >> 5;
            const int zc4 = u & 31;
            const float4* Zp = (const float4*)z + (size_t)bi*512*32 + zc4;
            const float* a0p = aL + hg*516;
            const float* a1p = aL + (hg+4)*516;
            const float* a2p = aL + (hg+8)*516;
            for (int jt = j0; jt < j1; jt += 8) {
                float4 zr[8];
                #pragma unroll
                for (int e = 0; e < 8; ++e) zr[e] = Zp[(size_t)(jt+e)*32];
                float4 a0q0 = *(const float4*)(a0p + jt), a0q1 = *(const float4*)(a0p + jt + 4);
                float4 a1q0 = *(const float4*)(a1p + jt), a1q1 = *(const float4*)(a1p + jt + 4);
                float4 a2q0 = *(const float4*)(a2p + jt), a2q1 = *(const float4*)(a2p + jt + 4);
                #pragma unroll
                for (int e = 0; e < 4; ++e) {
                    fma4(acc0, ((const float*)&a0q0)[e], zr[e]);
                    fma4(acc1, ((const float*)&a1q0)[e], zr[e]);
                    fma4(acc2, ((const float*)&a2q0)[e], zr[e]);
                }
                #pragma unroll
                for (int e = 0; e < 4; ++e) {
                    fma4(acc0, ((const float*)&a0q1)[e], zr[4+e]);
                    fma4(acc1, ((const float*)&a1q1)[e], zr[4+e]);
                    fma4(acc2, ((const float*)&a2q1)[e], zr[4+e]);
                }
            }
        } else if (u < 144) {
            typ = 1; const int v0 = u - 128;
            const int c4 = v0 & 3; hg = v0 >> 2;
            const float4* Vp = (const float4*)(ws + OFF_V) + (size_t)b*512*48;
            const float* a0p = aL + hg*516;
            const float* a1p = aL + (hg+4)*516;
            const float* a2p = aL + (hg+8)*516;
            for (int jt = j0; jt < j1; jt += 4) {
                float4 av0 = *(const float4*)(a0p + jt);
                float4 av1 = *(const float4*)(a1p + jt);
                float4 av2 = *(const float4*)(a2p + jt);
                #pragma unroll
                for (int e = 0; e < 4; ++e) {
                    size_t jb = (size_t)(jt+e)*48;
                    fma4(acc0, ((const float*)&av0)[e], Vp[jb + (hg  )*4 + c4]);
                    fma4(acc1, ((const float*)&av1)[e], Vp[jb + (hg+4)*4 + c4]);
                    fma4(acc2, ((const float*)&av2)[e], Vp[jb + (hg+8)*4 + c4]);
                }
            }
        } else {
            typ = 2; const int v0 = u - 144;
            const int po = v0 % 6; hg = v0 / 6;
            const float4* VPp = (const float4*)(ws + OFF_VP) + (size_t)b*512*72;
            const float* a0p = aL + hg*516;
            const float* a1p = aL + (hg+4)*516;
            const float* a2p = aL + (hg+8)*516;
            for (int jt = j0; jt < j1; jt += 4) {
                float4 av0 = *(const float4*)(a0p + jt);
                float4 av1 = *(const float4*)(a1p + jt);
                float4 av2 = *(const float4*)(a2p + jt);
                #pragma unroll
                for (int e = 0; e < 4; ++e) {
                    size_t jb = (size_t)(jt+e)*72;
                    fma4(acc0, ((const float*)&av0)[e], VPp[jb + (hg  )*6 + po]);
                    fma4(acc1, ((const float*)&av1)[e], VPp[jb + (hg+4)*6 + po]);
                    fma4(acc2, ((const float*)&av2)[e], VPp[jb + (hg+8)*6 + po]);
                }
            }
        }
    }
    __syncthreads();                       // all reads of aL done
    float4* sc4 = (float4*)aL;             // reuse aL as reduction scratch
    if (t < 504 && seg > 0) {
        int si = ((seg-1)*168 + u)*3;
        sc4[si] = acc0; sc4[si+1] = acc1; sc4[si+2] = acc2;
    }
    __syncthreads();

    if (t < 168) {
        #pragma unroll
        for (int ss = 0; ss < 2; ++ss) {
            int si = (ss*168 + t)*3;
            add4(acc0, sc4[si]); add4(acc1, sc4[si+1]); add4(acc2, sc4[si+2]);
        }
        float4* cat4 = (float4*)(ws + OFF_CAT);
        const size_t cb = (size_t)bi * 528;          // 2112/4
        if (typ == 0) {
            const int zc4 = u & 31;
            cat4[cb + 144 + (hg  )*32 + zc4] = acc0;
            cat4[cb + 144 + (hg+4)*32 + zc4] = acc1;
            cat4[cb + 144 + (hg+8)*32 + zc4] = acc2;
        } else if (typ == 1) {
            const int c4 = (u-128) & 3;
            cat4[cb + (hg  )*4 + c4] = acc0;
            cat4[cb + (hg+4)*4 + c4] = acc1;
            cat4[cb + (hg+8)*4 + c4] = acc2;
        } else {
            const int po = (u-144) % 6;
            optgS4[(hg  )*6 + po] = acc0;
            optgS4[(hg+4)*6 + po] = acc1;
            optgS4[(hg+8)*6 + po] = acc2;
        }
    }
    __syncthreads();

    if (t < 96) {
        const float* og = (const float*)optgS4;
        int h = t >> 3, p = t & 7;
        int o = h*24 + p*3;
        float d0 = og[o]   - tiL[0];
        float d1 = og[o+1] - tiL[1];
        float d2 = og[o+2] - tiL[2];
        float ox = RiL[0]*d0 + RiL[3]*d1 + RiL[6]*d2;
        float oy = RiL[1]*d0 + RiL[4]*d1 + RiL[7]*d2;
        float oz = RiL[2]*d0 + RiL[5]*d1 + RiL[8]*d2;
        float* cat = ws + OFF_CAT + (size_t)bi*CATD;
        cat[192 + o]     = ox;
        cat[192 + o + 1] = oy;
        cat[192 + o + 2] = oz;
        cat[480 + h*8 + p] = sqrtf(ox*ox + oy*oy + oz*oz + 1e-8f);
    }
}

// ---------------- Kernel 4: out = cat @ Wout (cat via scalar loads) ---------
__global__ __launch_bounds__(384) void k_out(
    const float* __restrict__ Wout, const float* __restrict__ ws, float* __restrict__ out)
{
    const int t = threadIdx.x;                 // col 0..383
    const int row0 = blockIdx.x * 4;
    const float* c0 = ws + OFF_CAT + (size_t)(row0+0)*CATD;
    const float* c1 = c0 + CATD;
    const float* c2 = c1 + CATD;
    const float* c3 = c2 + CATD;
    float a0 = 0.f, a1 = 0.f, a2 = 0.f, a3 = 0.f;
    #pragma unroll 16
    for (int r = 0; r < CATD; ++r) {
        float w = Wout[(size_t)r*384 + t];
        a0 += c0[r]*w; a1 += c1[r]*w; a2 += c2[r]*w; a3 += c3[r]*w;
    }
    out[(size_t)(row0+0)*384 + t] = a0;
    out[(size_t)(row0+1)*384 + t] = a1;
    out[(size_t)(row0+2)*384 + t] = a2;
    out[(size_t)(row0+3)*384 + t] = a3;
}

extern "C" void kernel_launch(void* const* d_in, const int* in_sizes, int n_in,
                              void* d_out, int out_size, void* d_ws, size_t ws_size,
                              hipStream_t stream)
{
    const float* s    = (const float*)d_in[0];
    const float* z    = (const float*)d_in[1];
    const float* R    = (const float*)d_in[2];
    const float* tt   = (const float*)d_in[3];
    const float* Wq   = (const float*)d_in[4];
    const float* Wk   = (const float*)d_in[5];
    const float* Wv   = (const float*)d_in[6];
    const float* Wqp  = (const float*)d_in[7];
    const float* Wkp  = (const float*)d_in[8];
    const float* Wvp  = (const float*)d_in[9];
    const float* Wb   = (const float*)d_in[10];
    const float* hw   = (const float*)d_in[11];
    const float* Wout = (const float*)d_in[12];
    float* ws  = (float*)d_ws;
    float* out = (float*)d_out;

    hipLaunchKernelGGL(k_proj, dim3(BN/2),        dim3(512), 0, stream,
                       s, R, tt, Wq, Wk, Wv, Wqp, Wkp, Wvp, ws);
    hipLaunchKernelGGL(k_bias, dim3(BN*NN/64),    dim3(256), 0, stream, z, Wb, ws);
    hipLaunchKernelGGL(k_attn, dim3(BN),          dim3(512), 0, stream, z, R, tt, hw, ws);
    hipLaunchKernelGGL(k_out,  dim3(BN/4),        dim3(384), 0, stream, Wout, ws, out);
}